// Round 1
// baseline (307.260 us; speedup 1.0000x reference)
//
#include <hip/hip_runtime.h>

#define NB 32
#define NC 128
#define NH 56
#define NW 56
#define HP 58
#define WP 58
#define KK 1152
#define NPOS 3136                       // 56*56
#define XT_BYTES (NB * HP * WP * NC * 2)  // 27,557,888
#define AW_OFF XT_BYTES
#define AW_BYTES (512 * KK * 2)           // 1,179,648
#define CW_OFF (AW_OFF + AW_BYTES)

typedef __attribute__((ext_vector_type(8))) short s16x8;
typedef __attribute__((ext_vector_type(4))) float f32x4;
typedef unsigned int u32;

__device__ __forceinline__ unsigned short f2bf(float f) {
    union { float f; unsigned int u; } v; v.f = f;
    unsigned int u = v.u + 0x7fffu + ((v.u >> 16) & 1u);
    return (unsigned short)(u >> 16);
}

__device__ __forceinline__ void gld16(const void* g, void* l) {
    __builtin_amdgcn_global_load_lds(
        (const __attribute__((address_space(1))) u32*)g,
        (__attribute__((address_space(3))) u32*)l, 16, 0, 0);
}

// ---- prologue 1: pad + transpose x [B,C,56,56]f32 -> x_t [B,58,58,C]bf16 ----
__global__ void k_xpose(const float* __restrict__ x, unsigned short* __restrict__ xt) {
    __shared__ float tile[32][29];
    int blk = blockIdx.x;
    int ct = blk & 3, xti = (blk >> 2) & 1, by = blk >> 3;
    int b = by / NH, y = by % NH;
    int x0 = xti * 28, ic0 = ct * 32;
    int tid = threadIdx.x;
#pragma unroll
    for (int p = 0; p < 4; ++p) {
        int e = p * 256 + tid;
        if (e < 896) {
            int i = e / 28, j = e % 28;
            tile[i][j] = x[((b * NC + ic0 + i) * NH + y) * NW + x0 + j];
        }
    }
    __syncthreads();
#pragma unroll
    for (int p = 0; p < 4; ++p) {
        int e = p * 256 + tid;
        if (e < 896) {
            int i = e & 31, j = e >> 5;  // 896 = 28*32 exact
            xt[((b * HP + y + 1) * WP + (x0 + j + 1)) * NC + ic0 + i] = f2bf(tile[i][j]);
        }
    }
}

// ---- prologue 2: w [4,128,128,3,3]f32 -> A' [m=512][k'=(ky*3+kx)*128+ic] bf16 ----
__global__ void k_wconv(const float* __restrict__ w, unsigned short* __restrict__ aw) {
    int idx = blockIdx.x * 256 + threadIdx.x;
    if (idx >= 512 * KK) return;
    int m = idx / KK, k = idx % KK;
    int g = k >> 7, ic = k & 127;
    aw[idx] = f2bf(w[(m * 128 + ic) * 9 + g]);
}

// ---- prologue 3: cw = softmax_rank(cw_row + cw_col), [4][3136] f32 ----
__global__ void k_cw(const float* __restrict__ cwr, const float* __restrict__ cwc,
                     float* __restrict__ cw) {
    int pos = blockIdx.x * 256 + threadIdx.x;
    if (pos >= NPOS) return;
    int y = pos / NW, x = pos % NW;
    float v0 = cwr[y] + cwc[x];
    float v1 = cwr[56 + y] + cwc[56 + x];
    float v2 = cwr[112 + y] + cwc[112 + x];
    float v3 = cwr[168 + y] + cwc[168 + x];
    float m = fmaxf(fmaxf(v0, v1), fmaxf(v2, v3));
    float e0 = expf(v0 - m), e1 = expf(v1 - m), e2 = expf(v2 - m), e3 = expf(v3 - m);
    float s = 1.0f / (e0 + e1 + e2 + e3);
    cw[pos] = e0 * s; cw[NPOS + pos] = e1 * s;
    cw[2 * NPOS + pos] = e2 * s; cw[3 * NPOS + pos] = e3 * s;
}

// ---- main: fused implicit-GEMM conv + rank combine + biases ----
// block: 512 thr (8 waves), M=512 (4 ranks x 128 ch), N=64 positions, K=1152
__global__ void __launch_bounds__(512) k_main(
    const unsigned short* __restrict__ xt, const unsigned short* __restrict__ aw,
    const float* __restrict__ cw, const float* __restrict__ brow,
    const float* __restrict__ bcol, const float* __restrict__ bch,
    float* __restrict__ out) {
    __shared__ __align__(16) unsigned char lds[36864];
    unsigned char* ldsA = lds;           // [512 m][64 B = 32 k bf16]
    unsigned char* ldsB = lds + 32768;   // [64 n][64 B = 32 k bf16]

    const int tid = threadIdx.x;
    const int lane = tid & 63;
    const int wv = tid >> 6;
    const int blk = blockIdx.x;
    const int b = blk / 49;
    const int tile0 = (blk % 49) * 64;

    // A staging: wave wv handles chunks q=wv*4+c, 16 rows each, lane->(row,16B chunk)
    const unsigned char* gA[4];
    unsigned char* lA[4];
    const unsigned char* awb = (const unsigned char*)aw;
#pragma unroll
    for (int c = 0; c < 4; ++c) {
        int q = wv * 4 + c;
        int m = q * 16 + (lane >> 2);
        gA[c] = awb + m * (KK * 2) + (lane & 3) * 16;
        lA[c] = ldsA + q * 1024 + lane * 16;
    }

    // B staging: waves 0..3, 16 positions each
    const unsigned char* gB = nullptr;
    unsigned char* lB = nullptr;
    if (wv < 4) {
        int nl = wv * 16 + (lane >> 2);
        int ng = tile0 + nl;
        int yy = ng / 56, xx = ng % 56;
        gB = (const unsigned char*)xt + (size_t)b * (HP * WP * NC * 2)
           + ((yy + 1) * WP + (xx + 1)) * (NC * 2) + (lane & 3) * 16;
        lB = ldsB + wv * 1024 + lane * 16;
    }

    // fragment LDS byte offsets (constant across K steps)
    int a_off[4], b_off[4];
#pragma unroll
    for (int r = 0; r < 4; ++r)
        a_off[r] = ((r * 8 + wv) * 16 + (lane & 15)) * 64 + (lane >> 4) * 16;
#pragma unroll
    for (int t = 0; t < 4; ++t)
        b_off[t] = (t * 16 + (lane & 15)) * 64 + (lane >> 4) * 16;

    f32x4 acc[4][4] = {};  // [rank][ntile]

    for (int s = 0; s < 36; ++s) {
        if (s) __syncthreads();
        int g = s >> 2;                 // filter tap 0..8
        int dy = g / 3 - 1, dx = g % 3 - 1;
        if (wv < 4) {
            int boff = ((dy * WP + dx) * NC + (s & 3) * 32) * 2;
            gld16(gB + boff, lB);
        }
#pragma unroll
        for (int c = 0; c < 4; ++c)
            gld16(gA[c] + s * 64, lA[c]);
        __syncthreads();

        s16x8 bf[4];
#pragma unroll
        for (int t = 0; t < 4; ++t)
            bf[t] = *(const s16x8*)(ldsB + b_off[t]);
#pragma unroll
        for (int r = 0; r < 4; ++r) {
            s16x8 af = *(const s16x8*)(ldsA + a_off[r]);
#pragma unroll
            for (int t = 0; t < 4; ++t)
                acc[r][t] = __builtin_amdgcn_mfma_f32_16x16x32_bf16(af, bf[t], acc[r][t], 0, 0, 0);
        }
    }

    // epilogue: combine ranks with cw, add biases, store fp32
    const int quad = lane >> 4, l15 = lane & 15;
#pragma unroll
    for (int t = 0; t < 4; ++t) {
        int ng = tile0 + t * 16 + l15;
        int yy = ng / 56, xx = ng % 56;
        float c0 = cw[ng], c1 = cw[NPOS + ng], c2 = cw[2 * NPOS + ng], c3 = cw[3 * NPOS + ng];
        float rb = brow[yy] + bcol[xx];
#pragma unroll
        for (int r = 0; r < 4; ++r) {
            int ch = wv * 16 + quad * 4 + r;
            float v = acc[0][t][r] * c0 + acc[1][t][r] * c1 + acc[2][t][r] * c2 + acc[3][t][r] * c3;
            out[((size_t)b * NC + ch) * NPOS + ng] = v + bch[ch] + rb;
        }
    }
}

extern "C" void kernel_launch(void* const* d_in, const int* in_sizes, int n_in,
                              void* d_out, int out_size, void* d_ws, size_t ws_size,
                              hipStream_t stream) {
    const float* x    = (const float*)d_in[0];
    const float* w    = (const float*)d_in[1];
    const float* cwr  = (const float*)d_in[2];
    const float* cwc  = (const float*)d_in[3];
    const float* brow = (const float*)d_in[4];
    const float* bcol = (const float*)d_in[5];
    const float* bch  = (const float*)d_in[6];
    float* out = (float*)d_out;

    unsigned char* ws = (unsigned char*)d_ws;
    unsigned short* xt = (unsigned short*)ws;
    unsigned short* aw = (unsigned short*)(ws + AW_OFF);
    float* cwv = (float*)(ws + CW_OFF);

    hipMemsetAsync(xt, 0, XT_BYTES, stream);              // zero halo of x_t
    k_xpose<<<NB * NH * 8, 256, 0, stream>>>(x, xt);      // 14336 blocks
    k_wconv<<<(512 * KK) / 256, 256, 0, stream>>>(w, aw); // 2304 blocks
    k_cw<<<(NPOS + 255) / 256, 256, 0, stream>>>(cwr, cwc, cwv);
    k_main<<<NB * 49, 512, 0, stream>>>(xt, aw, cwv, brow, bcol, bch, out);
}

// Round 2
// 261.475 us; speedup vs baseline: 1.1751x; 1.1751x over previous
//
#include <hip/hip_runtime.h>

#define NB 32
#define NC 128
#define NH 56
#define NW 56
#define HP 58
#define WP 58
#define KK 1152
#define NPOS 3136                         // 56*56
#define XT_BYTES (NB * HP * WP * NC * 2)  // 27,557,888
#define AW_OFF XT_BYTES

typedef __attribute__((ext_vector_type(8))) short s16x8;
typedef __attribute__((ext_vector_type(4))) float f32x4;
typedef unsigned int u32;

__device__ __forceinline__ unsigned short f2bf(float f) {
    union { float f; unsigned int u; } v; v.f = f;
    unsigned int u = v.u + 0x7fffu + ((v.u >> 16) & 1u);
    return (unsigned short)(u >> 16);
}

__device__ __forceinline__ void gld16(const void* g, void* l) {
    __builtin_amdgcn_global_load_lds(
        (const __attribute__((address_space(1))) u32*)g,
        (__attribute__((address_space(3))) u32*)l, 16, 0, 0);
}

// ---- prologue 1: pad + transpose x [B,C,56,56]f32 -> x_t [B,58,58,C]bf16 ----
// one block per (b, y); also zeroes this row's halo columns and edge rows.
__global__ void k_xpose(const float* __restrict__ x, unsigned short* __restrict__ xt) {
    __shared__ float tile[128 * 57];
    int blk = blockIdx.x;
    int b = blk / NH, y = blk % NH;
    int tid = threadIdx.x;
    const float* xb = x + (size_t)b * (NC * NPOS) + y * NW;
#pragma unroll
    for (int p = 0; p < 7; ++p) {
        int idx = p * 256 + tid;            // 1792 float4 = 7168 floats
        int c = idx / 14, i = idx - c * 14;
        float4 v = *(const float4*)(xb + c * NPOS + i * 4);
        float* tp = &tile[c * 57 + i * 4];
        tp[0] = v.x; tp[1] = v.y; tp[2] = v.z; tp[3] = v.w;
    }
    __syncthreads();
    unsigned short* xrow = xt + ((size_t)(b * HP + y + 1) * WP + 1) * NC;
#pragma unroll
    for (int p = 0; p < 4; ++p) {
        int idx = p * 256 + tid;            // 896 = 56 x-pos * 16 chunks
        if (idx < 896) {
            int xp = idx >> 4, cgi = idx & 15;
            s16x8 v8;
#pragma unroll
            for (int j = 0; j < 8; ++j)
                v8[j] = (short)f2bf(tile[(cgi * 8 + j) * 57 + xp]);
            *(s16x8*)(xrow + xp * NC + cgi * 8) = v8;
        }
    }
    // halo: left/right columns of this row
    if (tid < 128) {
        xt[((size_t)(b * HP + y + 1) * WP + 0) * NC + tid] = 0;
        xt[((size_t)(b * HP + y + 1) * WP + 57) * NC + tid] = 0;
    }
    // halo: top/bottom full rows
    if (y == 0) {
        unsigned short* r0 = xt + (size_t)(b * HP + 0) * WP * NC;
        for (int i = tid; i < WP * NC; i += 256) r0[i] = 0;
    }
    if (y == 55) {
        unsigned short* r57 = xt + (size_t)(b * HP + 57) * WP * NC;
        for (int i = tid; i < WP * NC; i += 256) r57[i] = 0;
    }
}

// ---- prologue 2: w [4,128,128,3,3]f32 -> A' [m=512][k'=(ky*3+kx)*128+ic] bf16 ----
__global__ void k_wconv(const float* __restrict__ w, unsigned short* __restrict__ aw) {
    int idx = blockIdx.x * 256 + threadIdx.x;
    if (idx >= 512 * KK) return;
    int m = idx / KK, k = idx - m * KK;
    int g = k >> 7, ic = k & 127;
    aw[idx] = f2bf(w[(m * 128 + ic) * 9 + g]);
}

// ---- main: fused implicit-GEMM conv + softmax rank combine + biases ----
// block: 512 thr (8 waves), M=512 (4 ranks x 128 ch), N=112 (2 image rows), K=1152
// double-buffered LDS (2 x 40KB), XOR-swizzled 16B chunks.
__global__ void __launch_bounds__(512, 2) k_main(
    const unsigned short* __restrict__ xt, const unsigned short* __restrict__ aw,
    const float* __restrict__ cwr, const float* __restrict__ cwc,
    const float* __restrict__ brow, const float* __restrict__ bcol,
    const float* __restrict__ bch, float* __restrict__ out) {
    __shared__ __align__(16) unsigned char lds[81920];   // 2 x (A 32KB + B 8KB)

    const int tid = threadIdx.x;
    const int lane = tid & 63;
    const int wv = tid >> 6;
    const int l15 = lane & 15, quad = lane >> 4;
    const int blk = blockIdx.x;
    const int b = blk / 28;
    const int tile0 = (blk - b * 28) * 112;

    // swizzle: global 16B chunk index this lane fetches (phys chunk = lane&3)
    const int cg = (lane & 3) ^ ((lane >> 3) & 3);

    // A staging: chunk c covers rows (wv*4+c)*16 .. +15
    const unsigned char* gA = (const unsigned char*)aw
        + (size_t)(wv * 64 + (lane >> 2)) * (KK * 2) + cg * 16;

    // B staging: waves 0..6 stage 16 n-rows each (112 total)
    const unsigned char* gB = nullptr;
    if (wv < 7) {
        int nl = wv * 16 + (lane >> 2);
        int pos = tile0 + nl;
        int yy = pos / 56, xx = pos - yy * 56;
        gB = (const unsigned char*)xt + (size_t)b * (HP * WP * NC * 2)
           + ((yy + 1) * WP + (xx + 1)) * (NC * 2) + cg * 16;
    }

    // fragment read offsets (swizzled chunk)
    const int sw = (l15 >> 1) & 3;
    const int a_base = (wv * 16 + l15) * 64 + ((quad ^ sw) * 16);          // + r*8192
    const int b_base = 32768 + l15 * 64 + ((quad ^ sw) * 16);              // + t*1024

    f32x4 acc[4][7] = {};

    auto stage = [&](int s, int pbuf) {
        unsigned char* Lb = lds + pbuf * 40960;
#pragma unroll
        for (int c = 0; c < 4; ++c)
            gld16(gA + c * (16 * KK * 2) + s * 64, Lb + (wv * 4 + c) * 1024 + lane * 16);
        if (wv < 7) {
            int g = s >> 2;
            int dy = (g * 11) >> 5;          // g/3 for g in [0,9)
            int dx = g - dy * 3;
            int boff = ((dy - 1) * WP + (dx - 1)) * (NC * 2) + (s & 3) * 64;
            gld16(gB + boff, Lb + 32768 + wv * 1024 + lane * 16);
        }
    };

    stage(0, 0);
    __syncthreads();

#pragma unroll 4
    for (int s = 0; s < 36; ++s) {
        const int cur = s & 1;
        if (s < 35) stage(s + 1, cur ^ 1);
        const unsigned char* Lb = lds + cur * 40960;
        s16x8 bf[7];
#pragma unroll
        for (int t = 0; t < 7; ++t)
            bf[t] = *(const s16x8*)(Lb + b_base + t * 1024);
#pragma unroll
        for (int r = 0; r < 4; ++r) {
            s16x8 af = *(const s16x8*)(Lb + a_base + r * 8192);
#pragma unroll
            for (int t = 0; t < 7; ++t)
                acc[r][t] = __builtin_amdgcn_mfma_f32_16x16x32_bf16(af, bf[t], acc[r][t], 0, 0, 0);
        }
        __syncthreads();
    }

    // epilogue: inline softmax over rank + combine + biases, fp32 store
#pragma unroll
    for (int t = 0; t < 7; ++t) {
        int pos = tile0 + t * 16 + l15;
        int yy = pos / 56, xx = pos - yy * 56;
        float v0 = cwr[yy]       + cwc[xx];
        float v1 = cwr[56 + yy]  + cwc[56 + xx];
        float v2 = cwr[112 + yy] + cwc[112 + xx];
        float v3 = cwr[168 + yy] + cwc[168 + xx];
        float mx = fmaxf(fmaxf(v0, v1), fmaxf(v2, v3));
        float e0 = __expf(v0 - mx), e1 = __expf(v1 - mx);
        float e2 = __expf(v2 - mx), e3 = __expf(v3 - mx);
        float inv = 1.0f / (e0 + e1 + e2 + e3);
        float c0 = e0 * inv, c1 = e1 * inv, c2 = e2 * inv, c3 = e3 * inv;
        float rb = brow[yy] + bcol[xx];
#pragma unroll
        for (int r = 0; r < 4; ++r) {
            int ch = wv * 16 + quad * 4 + r;
            float v = acc[0][t][r] * c0 + acc[1][t][r] * c1
                    + acc[2][t][r] * c2 + acc[3][t][r] * c3;
            out[((size_t)b * NC + ch) * NPOS + pos] = v + bch[ch] + rb;
        }
    }
}

extern "C" void kernel_launch(void* const* d_in, const int* in_sizes, int n_in,
                              void* d_out, int out_size, void* d_ws, size_t ws_size,
                              hipStream_t stream) {
    const float* x    = (const float*)d_in[0];
    const float* w    = (const float*)d_in[1];
    const float* cwr  = (const float*)d_in[2];
    const float* cwc  = (const float*)d_in[3];
    const float* brow = (const float*)d_in[4];
    const float* bcol = (const float*)d_in[5];
    const float* bch  = (const float*)d_in[6];
    float* out = (float*)d_out;

    unsigned char* ws = (unsigned char*)d_ws;
    unsigned short* xt = (unsigned short*)ws;
    unsigned short* aw = (unsigned short*)(ws + AW_OFF);

    k_xpose<<<NB * NH, 256, 0, stream>>>(x, xt);           // 1792 blocks
    k_wconv<<<(512 * KK) / 256, 256, 0, stream>>>(w, aw);  // 2304 blocks
    k_main<<<NB * 28, 512, 0, stream>>>(xt, aw, cwr, cwc, brow, bcol, bch, out);
}

// Round 3
// 251.684 us; speedup vs baseline: 1.2208x; 1.0389x over previous
//
#include <hip/hip_runtime.h>

#define NB 32
#define NC 128
#define NH 56
#define NW 56
#define HP 58
#define WP 58
#define KK 1152
#define NPOS 3136                         // 56*56
#define XT_BYTES (NB * HP * WP * NC * 2)  // 27,557,888
#define AW_OFF XT_BYTES

typedef __attribute__((ext_vector_type(8))) short s16x8;
typedef __attribute__((ext_vector_type(4))) float f32x4;
typedef unsigned int u32;

__device__ __forceinline__ unsigned short f2bf(float f) {
    union { float f; unsigned int u; } v; v.f = f;
    unsigned int u = v.u + 0x7fffu + ((v.u >> 16) & 1u);
    return (unsigned short)(u >> 16);
}

__device__ __forceinline__ void gld16(const void* g, void* l) {
    __builtin_amdgcn_global_load_lds(
        (const __attribute__((address_space(1))) u32*)g,
        (__attribute__((address_space(3))) u32*)l, 16, 0, 0);
}

// ---- prologue 1: pad + transpose x [B,C,56,56]f32 -> x_t [B,58,58,C]bf16 ----
// one block per (b, y); bf16 LDS tile (14.6 KB) for occupancy.
__global__ void k_xpose(const float* __restrict__ x, unsigned short* __restrict__ xt) {
    __shared__ unsigned short tile[128 * 57];
    int blk = blockIdx.x;
    int b = blk / NH, y = blk % NH;
    int tid = threadIdx.x;
    const float* xb = x + (size_t)b * (NC * NPOS) + y * NW;
#pragma unroll
    for (int p = 0; p < 7; ++p) {
        int idx = p * 256 + tid;            // 1792 float4 = 7168 floats
        int c = idx / 14, i = idx - c * 14;
        float4 v = *(const float4*)(xb + c * NPOS + i * 4);
        unsigned short* tp = &tile[c * 57 + i * 4];
        tp[0] = f2bf(v.x); tp[1] = f2bf(v.y); tp[2] = f2bf(v.z); tp[3] = f2bf(v.w);
    }
    __syncthreads();
    unsigned short* xrow = xt + ((size_t)(b * HP + y + 1) * WP + 1) * NC;
#pragma unroll
    for (int p = 0; p < 4; ++p) {
        int idx = p * 256 + tid;            // 896 = 56 x-pos * 16 chunks
        if (idx < 896) {
            int xp = idx >> 4, cgi = idx & 15;
            s16x8 v8;
#pragma unroll
            for (int j = 0; j < 8; ++j)
                v8[j] = (short)tile[(cgi * 8 + j) * 57 + xp];
            *(s16x8*)(xrow + xp * NC + cgi * 8) = v8;
        }
    }
    // halo: left/right columns of this row
    if (tid < 128) {
        xt[((size_t)(b * HP + y + 1) * WP + 0) * NC + tid] = 0;
        xt[((size_t)(b * HP + y + 1) * WP + 57) * NC + tid] = 0;
    }
    // halo: top/bottom full rows
    if (y == 0) {
        unsigned short* r0 = xt + (size_t)(b * HP + 0) * WP * NC;
        for (int i = tid; i < WP * NC; i += 256) r0[i] = 0;
    }
    if (y == 55) {
        unsigned short* r57 = xt + (size_t)(b * HP + 57) * WP * NC;
        for (int i = tid; i < WP * NC; i += 256) r57[i] = 0;
    }
}

// ---- prologue 2: w [4,128,128,3,3]f32 -> A fragments in exact MFMA lane order ----
// aw2[s][mt][lane][j]: s = K32-step (36), mt = 16-row m-tile (32), lane 0..63, j 0..7
// m = mt*16 + (lane&15); k_global = s*32 + (lane>>4)*8 + j
__global__ void k_wconv(const float* __restrict__ w, unsigned short* __restrict__ aw) {
    int idx = blockIdx.x * 256 + threadIdx.x;   // 589824 total
    if (idx >= 512 * KK) return;
    int j = idx & 7, lane = (idx >> 3) & 63, mt = (idx >> 9) & 31, s = idx >> 14;
    int m = mt * 16 + (lane & 15);
    int kg = s * 32 + (lane >> 4) * 8 + j;
    int g = kg >> 7, ic = kg & 127;
    aw[idx] = f2bf(w[(m * 128 + ic) * 9 + g]);
}

// ---- main: fused implicit-GEMM conv + softmax rank combine + biases ----
// 8 waves, M=512 (4 ranks x 128 ch), N=112 (2 image rows), K=1152.
// A: global->VGPR direct (fragment-ordered, L2-resident), double-buffered.
// B: global_load_lds into 2 x 14KB LDS, K=64 stages (18 barriers total).
__global__ void __launch_bounds__(512, 2) k_main(
    const unsigned short* __restrict__ xt, const unsigned short* __restrict__ aw,
    const float* __restrict__ cwr, const float* __restrict__ cwc,
    const float* __restrict__ brow, const float* __restrict__ bcol,
    const float* __restrict__ bch, float* __restrict__ out) {
    __shared__ __align__(16) unsigned char ldsB[28672];   // 2 x 112 rows x 128 B

    const int tid = threadIdx.x;
    const int lane = tid & 63;
    const int wv = tid >> 6;
    const int l15 = lane & 15, quad = lane >> 4;
    const int blk = blockIdx.x;
    const int b = blk / 28;
    const int tile0 = (blk - b * 28) * 112;

    // ---- B staging pointers: wave wv (0..6) stages rows wv*16..+15, 128 B each.
    // gld16 #h covers rows +h*8+(lane>>3), phys chunk lane&7; fetch swizzled
    // global chunk (lane&7)^(lane>>3) so frag reads are bank-uniform.
    const unsigned char* gB0 = nullptr;
    const unsigned char* gB1 = nullptr;
    if (wv < 7) {
#pragma unroll
        for (int h = 0; h < 2; ++h) {
            int row = wv * 16 + h * 8 + (lane >> 3);
            int pos = tile0 + row;
            int yy = pos / 56, xx = pos - yy * 56;
            const unsigned char* p = (const unsigned char*)xt
                + (size_t)b * (HP * WP * NC * 2)
                + ((yy + 1) * WP + (xx + 1)) * (NC * 2)
                + (((lane & 7) ^ (lane >> 3)) * 16);
            if (h == 0) gB0 = p; else gB1 = p;
        }
    }

    // ---- A direct-load base: + ((s*32 + r*8) << 10) per fragment
    const unsigned char* gA = (const unsigned char*)aw + wv * 1024 + lane * 16;

    s16x8 Areg[2][2][4];   // [set][kk][r]
    f32x4 acc[4][7] = {};

    auto aload = [&](int st, int set) {
#pragma unroll
        for (int kk = 0; kk < 2; ++kk)
#pragma unroll
            for (int r = 0; r < 4; ++r)
                Areg[set][kk][r] = *(const s16x8*)(gA + (((2 * st + kk) * 32 + r * 8) << 10));
    };

    auto bstage = [&](int st, int pbuf) {
        if (wv < 7) {
            int g = st >> 1;
            int dy = (g * 11) >> 5;          // g/3 for g in [0,9)
            int dx = g - dy * 3;
            int off = ((dy - 1) * WP + (dx - 1)) * (NC * 2) + (st & 1) * 128;
            unsigned char* L = ldsB + pbuf * 14336 + wv * 2048;
            gld16(gB0 + off, L);
            gld16(gB1 + off, L + 1024);
        }
    };

    bstage(0, 0);
    aload(0, 0);
    __syncthreads();

    for (int st = 0; st < 18; ++st) {
        const int cur = st & 1;
        if (st < 17) {
            bstage(st + 1, cur ^ 1);
            aload(st + 1, cur ^ 1);
        }
        const unsigned char* L = ldsB + cur * 14336;
#pragma unroll
        for (int kk = 0; kk < 2; ++kk) {
            s16x8 bf[7];
#pragma unroll
            for (int t = 0; t < 7; ++t)
                bf[t] = *(const s16x8*)(L + (t * 16 + l15) * 128
                                          + (((kk * 4 + quad) ^ (l15 & 7)) * 16));
#pragma unroll
            for (int r = 0; r < 4; ++r)
#pragma unroll
                for (int t = 0; t < 7; ++t)
                    acc[r][t] = __builtin_amdgcn_mfma_f32_16x16x32_bf16(
                        Areg[cur][kk][r], bf[t], acc[r][t], 0, 0, 0);
        }
        __syncthreads();
    }

    // epilogue: inline softmax over rank + combine + biases, fp32 store
#pragma unroll
    for (int t = 0; t < 7; ++t) {
        int pos = tile0 + t * 16 + l15;
        int yy = pos / 56, xx = pos - yy * 56;
        float v0 = cwr[yy]       + cwc[xx];
        float v1 = cwr[56 + yy]  + cwc[56 + xx];
        float v2 = cwr[112 + yy] + cwc[112 + xx];
        float v3 = cwr[168 + yy] + cwc[168 + xx];
        float mx = fmaxf(fmaxf(v0, v1), fmaxf(v2, v3));
        float e0 = __expf(v0 - mx), e1 = __expf(v1 - mx);
        float e2 = __expf(v2 - mx), e3 = __expf(v3 - mx);
        float inv = 1.0f / (e0 + e1 + e2 + e3);
        float c0 = e0 * inv, c1 = e1 * inv, c2 = e2 * inv, c3 = e3 * inv;
        float rb = brow[yy] + bcol[xx];
#pragma unroll
        for (int r = 0; r < 4; ++r) {
            int ch = wv * 16 + quad * 4 + r;
            float v = acc[0][t][r] * c0 + acc[1][t][r] * c1
                    + acc[2][t][r] * c2 + acc[3][t][r] * c3;
            out[((size_t)b * NC + ch) * NPOS + pos] = v + bch[ch] + rb;
        }
    }
}

extern "C" void kernel_launch(void* const* d_in, const int* in_sizes, int n_in,
                              void* d_out, int out_size, void* d_ws, size_t ws_size,
                              hipStream_t stream) {
    const float* x    = (const float*)d_in[0];
    const float* w    = (const float*)d_in[1];
    const float* cwr  = (const float*)d_in[2];
    const float* cwc  = (const float*)d_in[3];
    const float* brow = (const float*)d_in[4];
    const float* bcol = (const float*)d_in[5];
    const float* bch  = (const float*)d_in[6];
    float* out = (float*)d_out;

    unsigned char* ws = (unsigned char*)d_ws;
    unsigned short* xt = (unsigned short*)ws;
    unsigned short* aw = (unsigned short*)(ws + AW_OFF);

    k_xpose<<<NB * NH, 256, 0, stream>>>(x, xt);           // 1792 blocks
    k_wconv<<<(512 * KK) / 256, 256, 0, stream>>>(w, aw);  // 2304 blocks
    k_main<<<NB * 28, 512, 0, stream>>>(xt, aw, cwr, cwc, brow, bcol, bch, out);
}